// Round 3
// baseline (88.341 us; speedup 1.0000x reference)
//
#include <hip/hip_runtime.h>
#include <hip/hip_bf16.h>

// out[i,j] = sum_k relu(a@feats^T)[i,k] * ((b@feats^T)[j,k] <= 0)
// Na=Nb=1024, D=512, K=256.
//
// convert : f32 -> bf16 split planes. a -> (h,m); b,feats -> (h,m,l).
//           x = h + m + l with h=bf16(x), m=bf16(x-h), l=bf16(x-h-m).
// stage1  : MFMA bf16 16x16x32, direct L2 frag loads, no LDS.
//           part A (p = relu(a@f^T)):  3 MFMA/iter (ah*fh + ah*fm + am*fh) — relu is
//             continuous, so ~3e-4 abs error here is harmless.
//           part B (msk = (b@f^T<=0)): 6 MFMA/iter (hh,hm,mh,hl,lh,mm) — dropped terms
//             ~2^-24 rel -> sign decision f32-equivalent (keeps absmax at the stable 8.0).
// gemm2   : MFMA bf16: out = p @ msk^T (unchanged from round 2, verified).

typedef short bf16x8 __attribute__((ext_vector_type(8)));
typedef float f32x4  __attribute__((ext_vector_type(4)));

__device__ inline void split3(float x, __hip_bfloat16& h, __hip_bfloat16& m, __hip_bfloat16& l) {
    h = __float2bfloat16(x);
    float r1 = x - __bfloat162float(h);
    m = __float2bfloat16(r1);
    float r2 = r1 - __bfloat162float(m);
    l = __float2bfloat16(r2);
}

__global__ __launch_bounds__(256) void convert_kernel(
    const float* __restrict__ a, const float* __restrict__ b, const float* __restrict__ f,
    __hip_bfloat16* __restrict__ Ah, __hip_bfloat16* __restrict__ Am,
    __hip_bfloat16* __restrict__ Bh, __hip_bfloat16* __restrict__ Bm, __hip_bfloat16* __restrict__ Bl,
    __hip_bfloat16* __restrict__ Fh, __hip_bfloat16* __restrict__ Fm, __hip_bfloat16* __restrict__ Fl)
{
    const int t = blockIdx.x * 256 + threadIdx.x;   // 0..131071
    const int i4 = t * 4;

    // a: 1024x512 = 524288 els, 4/thread -> h,m planes
    {
        float4 v = *(const float4*)(a + i4);
        __hip_bfloat16 h[4] __attribute__((aligned(8)));
        __hip_bfloat16 m[4] __attribute__((aligned(8)));
        __hip_bfloat16 l;
        split3(v.x, h[0], m[0], l); split3(v.y, h[1], m[1], l);
        split3(v.z, h[2], m[2], l); split3(v.w, h[3], m[3], l);
        *(short4*)((short*)Ah + i4) = *(const short4*)h;
        *(short4*)((short*)Am + i4) = *(const short4*)m;
    }
    // b: 524288 els, 4/thread -> h,m,l planes
    {
        float4 v = *(const float4*)(b + i4);
        __hip_bfloat16 h[4] __attribute__((aligned(8)));
        __hip_bfloat16 m[4] __attribute__((aligned(8)));
        __hip_bfloat16 l[4] __attribute__((aligned(8)));
        split3(v.x, h[0], m[0], l[0]); split3(v.y, h[1], m[1], l[1]);
        split3(v.z, h[2], m[2], l[2]); split3(v.w, h[3], m[3], l[3]);
        *(short4*)((short*)Bh + i4) = *(const short4*)h;
        *(short4*)((short*)Bm + i4) = *(const short4*)m;
        *(short4*)((short*)Bl + i4) = *(const short4*)l;
    }
    // feats: 256x512 = 131072 els, 1/thread -> h,m,l planes
    {
        float x = f[t];
        __hip_bfloat16 h, m, l;
        split3(x, h, m, l);
        Fh[t] = h; Fm[t] = m; Fl[t] = l;
    }
}

__global__ __launch_bounds__(256) void stage1_kernel(
    const __hip_bfloat16* __restrict__ Ah, const __hip_bfloat16* __restrict__ Am,
    const __hip_bfloat16* __restrict__ Bh, const __hip_bfloat16* __restrict__ Bm,
    const __hip_bfloat16* __restrict__ Bl,
    const __hip_bfloat16* __restrict__ Fh, const __hip_bfloat16* __restrict__ Fm,
    const __hip_bfloat16* __restrict__ Fl,
    __hip_bfloat16* __restrict__ pbf, __hip_bfloat16* __restrict__ mbf)
{
    // 512 blocks: [0,256) -> part A (p), [256,512) -> part B (msk).
    // Block tile 32x32 (m x n), 4 waves in 2x2, wave tile 16x16, K=512.
    const int idx = blockIdx.x;
    const bool isA = idx < 256;
    const int t  = idx & 255;
    const int bi = t >> 3;               // 0..31
    const int bn = t & 7;                // 0..7
    const int m0 = bi * 32;
    const int n0 = bn * 32;

    const int tid  = threadIdx.x;
    const int w    = tid >> 6;
    const int lane = tid & 63;
    const int wi = w >> 1, wj = w & 1;
    const int l15 = lane & 15;
    const int q   = lane >> 4;

    const int ra = (m0 + wi * 16 + l15) * 512;   // row base in A/B planes
    const int rf = (n0 + wj * 16 + l15) * 512;   // row base in F planes

    f32x4 acc = {0.f, 0.f, 0.f, 0.f};

    if (isA) {
        const short* ah_p = (const short*)Ah + ra;
        const short* am_p = (const short*)Am + ra;
        const short* fh_p = (const short*)Fh + rf;
        const short* fm_p = (const short*)Fm + rf;
        #pragma unroll 4
        for (int k0 = 0; k0 < 512; k0 += 32) {
            const int ko = k0 + q * 8;
            bf16x8 ah = *(const bf16x8*)(ah_p + ko);
            bf16x8 am = *(const bf16x8*)(am_p + ko);
            bf16x8 fh = *(const bf16x8*)(fh_p + ko);
            bf16x8 fm = *(const bf16x8*)(fm_p + ko);
            acc = __builtin_amdgcn_mfma_f32_16x16x32_bf16(ah, fh, acc, 0, 0, 0);
            acc = __builtin_amdgcn_mfma_f32_16x16x32_bf16(ah, fm, acc, 0, 0, 0);
            acc = __builtin_amdgcn_mfma_f32_16x16x32_bf16(am, fh, acc, 0, 0, 0);
        }
        const int orow = m0 + wi * 16 + q * 4;
        const int ocol = n0 + wj * 16 + l15;
        #pragma unroll
        for (int r = 0; r < 4; r++)
            pbf[(size_t)(orow + r) * 256 + ocol] = __float2bfloat16(fmaxf(acc[r], 0.f));
    } else {
        const short* bh_p = (const short*)Bh + ra;
        const short* bm_p = (const short*)Bm + ra;
        const short* bl_p = (const short*)Bl + ra;
        const short* fh_p = (const short*)Fh + rf;
        const short* fm_p = (const short*)Fm + rf;
        const short* fl_p = (const short*)Fl + rf;
        #pragma unroll 4
        for (int k0 = 0; k0 < 512; k0 += 32) {
            const int ko = k0 + q * 8;
            bf16x8 bh = *(const bf16x8*)(bh_p + ko);
            bf16x8 bm = *(const bf16x8*)(bm_p + ko);
            bf16x8 bl = *(const bf16x8*)(bl_p + ko);
            bf16x8 fh = *(const bf16x8*)(fh_p + ko);
            bf16x8 fm = *(const bf16x8*)(fm_p + ko);
            bf16x8 fl = *(const bf16x8*)(fl_p + ko);
            acc = __builtin_amdgcn_mfma_f32_16x16x32_bf16(bh, fh, acc, 0, 0, 0);
            acc = __builtin_amdgcn_mfma_f32_16x16x32_bf16(bh, fm, acc, 0, 0, 0);
            acc = __builtin_amdgcn_mfma_f32_16x16x32_bf16(bm, fh, acc, 0, 0, 0);
            acc = __builtin_amdgcn_mfma_f32_16x16x32_bf16(bh, fl, acc, 0, 0, 0);
            acc = __builtin_amdgcn_mfma_f32_16x16x32_bf16(bl, fh, acc, 0, 0, 0);
            acc = __builtin_amdgcn_mfma_f32_16x16x32_bf16(bm, fm, acc, 0, 0, 0);
        }
        const int orow = m0 + wi * 16 + q * 4;
        const int ocol = n0 + wj * 16 + l15;
        #pragma unroll
        for (int r = 0; r < 4; r++)
            mbf[(size_t)(orow + r) * 256 + ocol] = __float2bfloat16(acc[r] <= 0.f ? 1.f : 0.f);
    }
}

__global__ __launch_bounds__(256) void gemm2_kernel(
    const __hip_bfloat16* __restrict__ p, const __hip_bfloat16* __restrict__ m,
    float* __restrict__ out)
{
    // out (1024x1024) = p (1024x256) @ m^T. Block 32(i) x 64(j), 4 waves 2x2,
    // wave tile 16x32. grid = 512.
    const int bi = blockIdx.x >> 4;
    const int bj = blockIdx.x & 15;
    const int i0 = bi * 32;
    const int j0 = bj * 64;

    const int tid  = threadIdx.x;
    const int w    = tid >> 6;
    const int lane = tid & 63;
    const int wi = w >> 1, wj = w & 1;
    const int l15 = lane & 15;
    const int q   = lane >> 4;

    const int arow  = i0 + wi * 16 + l15;
    const int jbase = j0 + wj * 32;
    const int brow0 = jbase + l15;
    const int brow1 = brow0 + 16;

    const short* ps = (const short*)p;
    const short* ms = (const short*)m;

    f32x4 acc0 = {0.f, 0.f, 0.f, 0.f};
    f32x4 acc1 = {0.f, 0.f, 0.f, 0.f};

    #pragma unroll
    for (int k0 = 0; k0 < 256; k0 += 32) {
        const int ko = k0 + q * 8;
        bf16x8 av = *(const bf16x8*)(ps + (size_t)arow  * 256 + ko);
        bf16x8 b0 = *(const bf16x8*)(ms + (size_t)brow0 * 256 + ko);
        bf16x8 b1 = *(const bf16x8*)(ms + (size_t)brow1 * 256 + ko);
        acc0 = __builtin_amdgcn_mfma_f32_16x16x32_bf16(av, b0, acc0, 0, 0, 0);
        acc1 = __builtin_amdgcn_mfma_f32_16x16x32_bf16(av, b1, acc1, 0, 0, 0);
    }

    const int orow = i0 + wi * 16 + q * 4;
    const int ocol = jbase + l15;
    #pragma unroll
    for (int r = 0; r < 4; r++) {
        out[(size_t)(orow + r) * 1024 + ocol]      = acc0[r];
        out[(size_t)(orow + r) * 1024 + ocol + 16] = acc1[r];
    }
}

extern "C" void kernel_launch(void* const* d_in, const int* in_sizes, int n_in,
                              void* d_out, int out_size, void* d_ws, size_t ws_size,
                              hipStream_t stream) {
    const float* a     = (const float*)d_in[0];   // 1024x512
    const float* b     = (const float*)d_in[1];   // 1024x512
    const float* feats = (const float*)d_in[2];   // 256x512
    float* out = (float*)d_out;                   // 1024x1024

    const size_t NAB = 1024 * 512;   // 524288
    const size_t NF  = 256 * 512;    // 131072
    __hip_bfloat16* w0 = (__hip_bfloat16*)d_ws;
    __hip_bfloat16* Ah = w0;
    __hip_bfloat16* Am = Ah + NAB;
    __hip_bfloat16* Bh = Am + NAB;
    __hip_bfloat16* Bm = Bh + NAB;
    __hip_bfloat16* Bl = Bm + NAB;
    __hip_bfloat16* Fh = Bl + NAB;
    __hip_bfloat16* Fm = Fh + NF;
    __hip_bfloat16* Fl = Fm + NF;
    __hip_bfloat16* pbf = Fl + NF;                // 1024x256
    __hip_bfloat16* mbf = pbf + 1024 * 256;       // 1024x256

    convert_kernel<<<512, 256, 0, stream>>>(a, b, feats, Ah, Am, Bh, Bm, Bl, Fh, Fm, Fl);
    stage1_kernel <<<512, 256, 0, stream>>>(Ah, Am, Bh, Bm, Bl, Fh, Fm, Fl, pbf, mbf);
    gemm2_kernel  <<<512, 256, 0, stream>>>(pbf, mbf, out);
}